// Round 1
// baseline (440.220 us; speedup 1.0000x reference)
//
#include <hip/hip_runtime.h>

#define DM    1024
#define HID   4096
#define NKEYS 65536
#define TOPK  6

// ---------------- q = Wq @ query + bq  (wave per row) ----------------
__global__ __launch_bounds__(256) void qproj_kernel(const float* __restrict__ Wq,
                                                    const float* __restrict__ query,
                                                    const float* __restrict__ bq,
                                                    float* __restrict__ q) {
    const int wave = threadIdx.x >> 6;
    const int lane = threadIdx.x & 63;
    const int h = blockIdx.x * 4 + wave;           // 1024 blocks * 4 waves = 4096 rows
    const float4* __restrict__ Wrow = (const float4*)(Wq + (size_t)h * DM);
    const float4* __restrict__ qv   = (const float4*)query;
    float acc = 0.f;
#pragma unroll
    for (int k = 0; k < 4; ++k) {
        float4 w = Wrow[lane + k * 64];
        float4 x = qv[lane + k * 64];
        acc += w.x * x.x + w.y * x.y + w.z * x.z + w.w * x.w;
    }
#pragma unroll
    for (int off = 32; off > 0; off >>= 1) acc += __shfl_down(acc, off);
    if (lane == 0) q[h] = acc + bq[h];
}

// ---------------- v_part[b] = sum over 16 rows of Wk^T * q ----------------
// 256 blocks, each handles 16 h-rows; thread t owns cols 4t..4t+3 (float4).
__global__ __launch_bounds__(256) void vproj_kernel(const float* __restrict__ Wk,
                                                    const float* __restrict__ q,
                                                    float* __restrict__ v_part) {
    const int t  = threadIdx.x;
    const int b  = blockIdx.x;
    const int h0 = b * 16;                          // 256 * 16 = 4096 rows
    float4 acc = {0.f, 0.f, 0.f, 0.f};
#pragma unroll 4
    for (int j = 0; j < 16; ++j) {
        const int h = h0 + j;
        const float qh = q[h];
        float4 w = ((const float4*)(Wk + (size_t)h * DM))[t];
        acc.x += w.x * qh; acc.y += w.y * qh; acc.z += w.z * qh; acc.w += w.w * qh;
    }
    ((float4*)(v_part + (size_t)b * DM))[t] = acc;
}

// ---------------- v[d] = sum_b v_part[b][d] ----------------
__global__ __launch_bounds__(256) void vreduce_kernel(const float* __restrict__ v_part,
                                                      float* __restrict__ v) {
    const int d = blockIdx.x * 256 + threadIdx.x;   // 4 blocks -> 1024 d's
    float acc = 0.f;
    for (int b = 0; b < 256; ++b) acc += v_part[(size_t)b * DM + d];
    v[d] = acc;
}

// ---------------- scores[r] = key_mat[r] . v  (wave per row) ----------------
__global__ __launch_bounds__(256) void score_kernel(const float* __restrict__ key_mat,
                                                    const float* __restrict__ v,
                                                    float* __restrict__ scores) {
    const int wave = threadIdx.x >> 6;
    const int lane = threadIdx.x & 63;
    const int r = blockIdx.x * 4 + wave;            // 16384 blocks * 4 waves = 65536 rows
    const float4* __restrict__ row = (const float4*)(key_mat + (size_t)r * DM);
    const float4* __restrict__ vv  = (const float4*)v;
    float acc = 0.f;
#pragma unroll
    for (int k = 0; k < 4; ++k) {
        float4 a = row[lane + k * 64];
        float4 b = vv[lane + k * 64];
        acc += a.x * b.x + a.y * b.y + a.z * b.z + a.w * b.w;
    }
#pragma unroll
    for (int off = 32; off > 0; off >>= 1) acc += __shfl_down(acc, off);
    if (lane == 0) scores[r] = acc;
}

// ---------------- single-block top-6 + mean of selected rows ----------------
__global__ __launch_bounds__(1024) void topk_mean_kernel(const float* __restrict__ scores,
                                                         const float* __restrict__ key_mat,
                                                         float* __restrict__ out) {
    const int t = threadIdx.x;
    const float NEG = -3.4e38f;

    // per-thread local top-6 over 64 strided scores
    float bv[TOPK]; int bi[TOPK];
#pragma unroll
    for (int j = 0; j < TOPK; ++j) { bv[j] = NEG; bi[j] = 0; }
    for (int j = 0; j < 64; ++j) {
        const int i = j * 1024 + t;                 // coalesced
        const float s = scores[i];
        if (s > bv[TOPK - 1]) {
            int p = TOPK - 1;
            while (p > 0 && bv[p - 1] < s) { bv[p] = bv[p - 1]; bi[p] = bi[p - 1]; --p; }
            bv[p] = s; bi[p] = i;
        }
    }

    __shared__ float cv[1024 * TOPK];
    __shared__ int   ci[1024 * TOPK];
    __shared__ float rv[1024];
    __shared__ int   rp[1024];
    __shared__ int   sel[TOPK];
#pragma unroll
    for (int j = 0; j < TOPK; ++j) { cv[t * TOPK + j] = bv[j]; ci[t * TOPK + j] = bi[j]; }
    __syncthreads();

    // 6 sequential argmax passes over the 6144 candidates
    for (int p = 0; p < TOPK; ++p) {
        float m = NEG; int mp = 0;
#pragma unroll
        for (int j = 0; j < TOPK; ++j) {
            const float val = cv[t * TOPK + j];
            if (val > m) { m = val; mp = t * TOPK + j; }
        }
        rv[t] = m; rp[t] = mp;
        __syncthreads();
        for (int s = 512; s > 0; s >>= 1) {
            if (t < s) {
                if (rv[t + s] > rv[t]) { rv[t] = rv[t + s]; rp[t] = rp[t + s]; }
            }
            __syncthreads();
        }
        if (t == 0) { sel[p] = ci[rp[0]]; cv[rp[0]] = NEG; }
        __syncthreads();
    }

    // out[t] = mean over the 6 selected key rows
    float acc = 0.f;
#pragma unroll
    for (int p = 0; p < TOPK; ++p) acc += key_mat[(size_t)sel[p] * DM + t];
    out[t] = acc * (1.0f / 6.0f);
}

extern "C" void kernel_launch(void* const* d_in, const int* in_sizes, int n_in,
                              void* d_out, int out_size, void* d_ws, size_t ws_size,
                              hipStream_t stream) {
    const float* query   = (const float*)d_in[0];   // [1024]
    const float* key_mat = (const float*)d_in[1];   // [65536, 1024]
    const float* Wq      = (const float*)d_in[2];   // [4096, 1024]
    const float* bq      = (const float*)d_in[3];   // [4096]
    const float* Wk      = (const float*)d_in[4];   // [4096, 1024]
    // const float* bk   = (const float*)d_in[5];   // bk.q is a uniform score shift -> cannot change top-k; skipped
    float* out = (float*)d_out;                     // [1024] f32

    float* ws      = (float*)d_ws;
    float* q       = ws;                            // 4096
    float* v_part  = q + HID;                       // 256*1024
    float* v       = v_part + 256 * DM;             // 1024
    float* scores  = v + DM;                        // 65536

    qproj_kernel  <<<HID / 4, 256, 0, stream>>>(Wq, query, bq, q);
    vproj_kernel  <<<256,     256, 0, stream>>>(Wk, q, v_part);
    vreduce_kernel<<<DM / 256,256, 0, stream>>>(v_part, v);
    score_kernel  <<<NKEYS/4, 256, 0, stream>>>(key_mat, v, scores);
    topk_mean_kernel<<<1,    1024, 0, stream>>>(scores, key_mat, out);
}

// Round 3
// 383.152 us; speedup vs baseline: 1.1489x; 1.1489x over previous
//
#include <hip/hip_runtime.h>

#define DM    1024
#define HID   4096
#define NKEYS 65536
#define TOPK  6
#define NEGF  (-3.4e38f)

typedef float fvec4 __attribute__((ext_vector_type(4)));

__device__ __forceinline__ fvec4 nt_load4(const float* p) {
    return __builtin_nontemporal_load((const fvec4*)p);
}

// ---------------- q = Wq @ query + bq  (wave per row) ----------------
__global__ __launch_bounds__(256) void qproj_kernel(const float* __restrict__ Wq,
                                                    const float* __restrict__ query,
                                                    const float* __restrict__ bq,
                                                    float* __restrict__ q) {
    const int wave = threadIdx.x >> 6;
    const int lane = threadIdx.x & 63;
    const int h = blockIdx.x * 4 + wave;           // 1024 blocks * 4 waves = 4096 rows
    const float* Wrow = Wq + (size_t)h * DM;
    const fvec4* __restrict__ qv = (const fvec4*)query;
    float acc = 0.f;
#pragma unroll
    for (int k = 0; k < 4; ++k) {
        fvec4 w = nt_load4(Wrow + (lane + k * 64) * 4);   // Wq streamed once
        fvec4 x = qv[lane + k * 64];
        acc += w.x * x.x + w.y * x.y + w.z * x.z + w.w * x.w;
    }
#pragma unroll
    for (int off = 32; off > 0; off >>= 1) acc += __shfl_down(acc, off);
    if (lane == 0) q[h] = acc + bq[h];
}

// ---------------- v_part[b] = sum over 16 rows of Wk^T * q ----------------
__global__ __launch_bounds__(256) void vproj_kernel(const float* __restrict__ Wk,
                                                    const float* __restrict__ q,
                                                    float* __restrict__ v_part) {
    const int t  = threadIdx.x;
    const int b  = blockIdx.x;
    const int h0 = b * 16;                          // 256 * 16 = 4096 rows
    fvec4 acc = {0.f, 0.f, 0.f, 0.f};
#pragma unroll 4
    for (int j = 0; j < 16; ++j) {
        const int h = h0 + j;
        const float qh = q[h];
        fvec4 w = nt_load4(Wk + (size_t)h * DM + t * 4);  // Wk streamed once
        acc += w * qh;
    }
    *(fvec4*)(v_part + (size_t)b * DM + t * 4) = acc;
}

// ---------------- v[d] = sum_b v_part[b][d]  (16 blocks x 64) ----------------
__global__ __launch_bounds__(64) void vreduce_kernel(const float* __restrict__ v_part,
                                                     float* __restrict__ v) {
    const int d = blockIdx.x * 64 + threadIdx.x;    // 16 blocks -> 1024 d's
    float acc = 0.f;
#pragma unroll 8
    for (int b = 0; b < 256; ++b) acc += v_part[(size_t)b * DM + d];
    v[d] = acc;
}

// ---------------- scores[r] = key_mat[r] . v  (wave per row) ----------------
__global__ __launch_bounds__(256) void score_kernel(const float* __restrict__ key_mat,
                                                    const float* __restrict__ v,
                                                    float* __restrict__ scores) {
    const int wave = threadIdx.x >> 6;
    const int lane = threadIdx.x & 63;
    const int r = blockIdx.x * 4 + wave;            // 16384 blocks * 4 waves = 65536 rows
    const float* row = key_mat + (size_t)r * DM;
    const fvec4* __restrict__ vv = (const fvec4*)v;
    float acc = 0.f;
#pragma unroll
    for (int k = 0; k < 4; ++k) {
        fvec4 a = nt_load4(row + (lane + k * 64) * 4);    // key_mat streamed once here
        fvec4 b = vv[lane + k * 64];
        acc += a.x * b.x + a.y * b.y + a.z * b.z + a.w * b.w;
    }
#pragma unroll
    for (int off = 32; off > 0; off >>= 1) acc += __shfl_down(acc, off);
    if (lane == 0) scores[r] = acc;
}

// ---------------- stage1: per-block top-6 over 256 scores ----------------
// 256 blocks x 256 threads; block b -> rows [256b, 256b+256); writes 6 (val,idx).
__global__ __launch_bounds__(256) void topk_stage1(const float* __restrict__ scores,
                                                   float* __restrict__ cand_v,
                                                   int* __restrict__ cand_i) {
    const int t = threadIdx.x, b = blockIdx.x;
    const int i = b * 256 + t;
    float cur = scores[i];

    __shared__ float wv[4];
    __shared__ int   wi[4];
    __shared__ float selv[TOPK];
    __shared__ int   seli[TOPK];

    for (int p = 0; p < TOPK; ++p) {
        float m = cur; int mi = i;
#pragma unroll
        for (int off = 32; off > 0; off >>= 1) {
            float ov = __shfl_down(m, off);
            int   oi = __shfl_down(mi, off);
            if (ov > m) { m = ov; mi = oi; }
        }
        const int lane = t & 63, w = t >> 6;
        if (lane == 0) { wv[w] = m; wi[w] = mi; }
        __syncthreads();
        if (t == 0) {
            float bm = wv[0]; int bix = wi[0];
#pragma unroll
            for (int j = 1; j < 4; ++j) if (wv[j] > bm) { bm = wv[j]; bix = wi[j]; }
            selv[p] = bm; seli[p] = bix;
        }
        __syncthreads();
        if (i == seli[p]) cur = NEGF;               // knock out the winner
    }
    if (t < TOPK) { cand_v[b * TOPK + t] = selv[t]; cand_i[b * TOPK + t] = seli[t]; }
}

// ---------------- stage2: top-6 of 1536 candidates + mean of rows ----------------
__global__ __launch_bounds__(256) void topk_stage2_mean(const float* __restrict__ cand_v,
                                                        const int* __restrict__ cand_i,
                                                        const float* __restrict__ key_mat,
                                                        float* __restrict__ out) {
    const int t = threadIdx.x;
    const int NC = 256 * TOPK;                      // 1536 candidates

    __shared__ float sv[NC];
    __shared__ int   si[NC];
    __shared__ float wv[4];
    __shared__ int   wi[4];
    __shared__ int   sel[TOPK];

#pragma unroll
    for (int j = 0; j < TOPK; ++j) {
        sv[t + j * 256] = cand_v[t + j * 256];
        si[t + j * 256] = cand_i[t + j * 256];
    }
    __syncthreads();

    for (int p = 0; p < TOPK; ++p) {
        float m = NEGF; int mp = 0;                 // mp = LDS position
#pragma unroll
        for (int j = 0; j < TOPK; ++j) {
            const int pos = t * TOPK + j;
            const float val = sv[pos];
            if (val > m) { m = val; mp = pos; }
        }
#pragma unroll
        for (int off = 32; off > 0; off >>= 1) {
            float ov = __shfl_down(m, off);
            int   op = __shfl_down(mp, off);
            if (ov > m) { m = ov; mp = op; }
        }
        const int lane = t & 63, w = t >> 6;
        if (lane == 0) { wv[w] = m; wi[w] = mp; }
        __syncthreads();
        if (t == 0) {
            float bm = wv[0]; int bp = wi[0];
#pragma unroll
            for (int j = 1; j < 4; ++j) if (wv[j] > bm) { bm = wv[j]; bp = wi[j]; }
            sel[p] = si[bp];
            sv[bp] = NEGF;                          // knock out for next pass
        }
        __syncthreads();
    }

    // out (1024 floats) as 256 x fvec4; mean of the 6 selected key rows
    fvec4 acc = {0.f, 0.f, 0.f, 0.f};
#pragma unroll
    for (int p = 0; p < TOPK; ++p) {
        fvec4 r = *(const fvec4*)(key_mat + (size_t)sel[p] * DM + t * 4);
        acc += r;
    }
    acc *= (1.0f / 6.0f);
    *(fvec4*)(out + t * 4) = acc;
}

extern "C" void kernel_launch(void* const* d_in, const int* in_sizes, int n_in,
                              void* d_out, int out_size, void* d_ws, size_t ws_size,
                              hipStream_t stream) {
    const float* query   = (const float*)d_in[0];   // [1024]
    const float* key_mat = (const float*)d_in[1];   // [65536, 1024]
    const float* Wq      = (const float*)d_in[2];   // [4096, 1024]
    const float* bq      = (const float*)d_in[3];   // [4096]
    const float* Wk      = (const float*)d_in[4];   // [4096, 1024]
    // bk skipped: bk.q is a uniform score shift -> cannot change top-k ordering
    float* out = (float*)d_out;                     // [1024] f32

    float* ws      = (float*)d_ws;
    float* q       = ws;                            // 4096
    float* v_part  = q + HID;                       // 256*1024
    float* v       = v_part + 256 * DM;             // 1024
    float* scores  = v + DM;                        // 65536
    float* cand_v  = scores + NKEYS;                // 1536
    int*   cand_i  = (int*)(cand_v + 256 * TOPK);   // 1536

    qproj_kernel     <<<HID / 4,  256, 0, stream>>>(Wq, query, bq, q);
    vproj_kernel     <<<256,      256, 0, stream>>>(Wk, q, v_part);
    vreduce_kernel   <<<DM / 64,  64,  0, stream>>>(v_part, v);
    score_kernel     <<<NKEYS / 4,256, 0, stream>>>(key_mat, v, scores);
    topk_stage1      <<<256,      256, 0, stream>>>(scores, cand_v, cand_i);
    topk_stage2_mean <<<1,        256, 0, stream>>>(cand_v, cand_i, key_mat, out);
}